// Round 20
// baseline (1257.621 us; speedup 1.0000x reference)
//
#include <hip/hip_runtime.h>
#include <hip/hip_bf16.h>
#include <hip/hip_cooperative_groups.h>

namespace cg = cooperative_groups;

#define H 4
#define C 64
#define D 256
#define NEG_SLOPE 0.2f
#define ESHIFT 8.0f
#define AGGC 48

typedef _Float16 half_t;
typedef __attribute__((ext_vector_type(8))) _Float16 half8v;
typedef __attribute__((ext_vector_type(4))) float f32x4;
typedef __attribute__((ext_vector_type(2))) float f32x2;

// Layouts:
//  - A / h ("xt"): fragment-linear tiled f16. panel = 16 rows; half-offset(r,c) =
//    (c>>5)*512 + ((c>>3)&3)*128 + r*8 + (c&7); wave frag load = panel*4096 + s*512 + lane*8.
//  - hp: FP8 (OCP e4m3), HEAD-MAJOR hp[h][n][64]. Scores from f32 accumulators.
//  - a_s / a_d: NODE-MAJOR [n][4].

// ---------------- CSR build ----------------
__global__ void count_kernel(const int* __restrict__ ei, int E, int N, int* __restrict__ counts) {
    int i = blockIdx.x * blockDim.x + threadIdx.x;
    if (i >= E + N) return;
    int d = (i < E) ? ei[E + i] : (i - E);
    atomicAdd(&counts[d], 1);
}

__global__ __launch_bounds__(1024) void scan1(const int* __restrict__ counts,
                                              int* __restrict__ row_ptr,
                                              int* __restrict__ bsum, int N) {
    __shared__ int wsum[16];
    int tid = threadIdx.x, lane = tid & 63, wid = tid >> 6;
    int idx = blockIdx.x * 1024 + tid;
    int v = (idx < N) ? counts[idx] : 0;
    int val = v;
    #pragma unroll
    for (int o = 1; o < 64; o <<= 1) {
        int t = __shfl_up(val, o);
        if (lane >= o) val += t;
    }
    if (lane == 63) wsum[wid] = val;
    __syncthreads();
    int woff = 0;
    #pragma unroll
    for (int w = 0; w < 16; w++) woff += (w < wid) ? wsum[w] : 0;
    if (idx < N) row_ptr[idx] = woff + val - v;
    if (tid == 1023) bsum[blockIdx.x] = woff + val;
}

__global__ __launch_bounds__(1024) void scan3(int* __restrict__ row_ptr,
                                              const int* __restrict__ bsum,
                                              int* __restrict__ cursor, int N, int nb) {
    __shared__ int woff_s;
    if (threadIdx.x == 0) {
        int w = 0;
        for (int i = 0; i < blockIdx.x; i++) w += bsum[i];
        woff_s = w;
        if (blockIdx.x == 0) {
            int tot = 0;
            for (int i = 0; i < nb; i++) tot += bsum[i];
            row_ptr[N] = tot;
        }
    }
    __syncthreads();
    int idx = blockIdx.x * 1024 + threadIdx.x;
    if (idx >= N) return;
    int r = row_ptr[idx] + woff_s;
    row_ptr[idx] = r;
    cursor[idx] = r;
}

__global__ void scatter_kernel(const int* __restrict__ ei, int E, int N,
                               int* __restrict__ cursor, int* __restrict__ csr_src) {
    int i = blockIdx.x * blockDim.x + threadIdx.x;
    if (i >= E + N) return;
    int s, d;
    if (i < E) { s = ei[i]; d = ei[E + i]; }
    else       { s = d = i - E; }
    int pos = atomicAdd(&cursor[d], 1);
    csr_src[pos] = s;
}

// ---------------- fp32 -> f16 tiled conversions (also zeroes counts) ----------------
__global__ void conv_x(const float* __restrict__ in, half_t* __restrict__ xt, int total,
                       int* __restrict__ counts, int N) {
    int t = blockIdx.x * blockDim.x + threadIdx.x;
    if (t < N) counts[t] = 0;
    if (t >= total) return;
    int i = t >> 5, o = t & 31;
    const float* src = in + (size_t)i * 256 + o * 8;
    float4 v0 = *(const float4*)src;
    float4 v1 = *(const float4*)(src + 4);
    half_t q[8] __attribute__((aligned(16)));
    q[0] = (half_t)v0.x; q[1] = (half_t)v0.y; q[2] = (half_t)v0.z; q[3] = (half_t)v0.w;
    q[4] = (half_t)v1.x; q[5] = (half_t)v1.y; q[6] = (half_t)v1.z; q[7] = (half_t)v1.w;
    size_t dst = (size_t)(i >> 4) * 4096 + (o >> 2) * 512 + (o & 3) * 128 + (i & 15) * 8;
    *(half8v*)(xt + dst) = *(half8v*)q;
}

__global__ void conv_w(const float* __restrict__ W, half_t* __restrict__ wt, int total) {
    int idx = blockIdx.x * blockDim.x + threadIdx.x;
    if (idx >= total) return;   // total = L*4*4*8*64
    int Lr = idx & 63;
    int s  = (idx >> 6) & 7;
    int cb = (idx >> 9) & 3;
    int h  = (idx >> 11) & 3;
    int l  = idx >> 13;
    int col = h * 64 + cb * 16 + (Lr & 15);
    int k0  = 32 * s + (Lr >> 4) * 8;
    half_t q[8] __attribute__((aligned(16)));
    #pragma unroll
    for (int j = 0; j < 8; j++)
        q[j] = (half_t)W[(size_t)l * 65536 + (size_t)(k0 + j) * 256 + col];
    *(half8v*)(wt + (size_t)idx * 8) = *(half8v*)q;
}

// ---------------- shared device bodies ----------------
#define AGG_BODY(g)                                                           \
    {                                                                         \
        int e_ = 2 * (g) + es;                                                \
        int s_ = __float_as_int(pk[wv][nn][e_][0]);                           \
        float a_ = pk[wv][nn][e_][1];                                         \
        const uint2 w_ = *(const uint2*)(hpb + (size_t)s_ * 64);              \
        f32x2 f0 = __builtin_amdgcn_cvt_pk_f32_fp8(w_.x, 0);                  \
        f32x2 f1 = __builtin_amdgcn_cvt_pk_f32_fp8(w_.x, 1);                  \
        f32x2 f2 = __builtin_amdgcn_cvt_pk_f32_fp8(w_.y, 0);                  \
        f32x2 f3 = __builtin_amdgcn_cvt_pk_f32_fp8(w_.y, 1);                  \
        asum += a_;                                                           \
        c0 = fmaf(f0.x, a_, c0); c1 = fmaf(f0.y, a_, c1);                     \
        c2 = fmaf(f1.x, a_, c2); c3 = fmaf(f1.y, a_, c3);                     \
        c4 = fmaf(f2.x, a_, c4); c5 = fmaf(f2.y, a_, c5);                     \
        c6 = fmaf(f3.x, a_, c6); c7 = fmaf(f3.y, a_, c7);                     \
    }

// ---------------- fused 4-layer cooperative kernel (grid sized by occupancy query) ----------------
__global__ __launch_bounds__(256, 4) void fused_layers(
    half_t* __restrict__ xt, unsigned char* __restrict__ hp,
    float* __restrict__ a_s, float* __restrict__ a_d,
    const half_t* __restrict__ wt, const float* __restrict__ att_src,
    const float* __restrict__ att_dst, const float* __restrict__ biases,
    const int* __restrict__ row_ptr, const int* __restrict__ csr_src,
    int N, int Npad, int L) {
    cg::grid_group gg = cg::this_grid();
    __shared__ float sp[2][4][16], sd[2][4][16];
    __shared__ float pk[4][4][AGGC][2];
    int tid = threadIdx.x;
    int cb = tid >> 6, lane = tid & 63;
    int rlo = lane & 15, q = lane >> 4;
    int wv = tid >> 6;
    int gemm_items = (Npad >> 5) * 4;        // 2-panel items x 4 heads
    int ngroups = (N + 15) >> 4;
    int agg_items = ngroups * 4;

    for (int l = 0; l < L; l++) {
        const half_t* Wl = wt + (size_t)l * 65536;
        const float* asrc = att_src + l * 256;
        const float* adst = att_dst + l * 256;
        const float* bias = biases + l * 256;

        // ---- GEMM phase ----
        for (int it = blockIdx.x; it < gemm_items; it += gridDim.x) {
            int h = it & 3, pg = it >> 2;
            const half_t* pb = Wl + (size_t)h * 16384 + (size_t)cb * 4096 + lane * 8;
            half8v B[8];
            #pragma unroll
            for (int s = 0; s < 8; s++) B[s] = *(const half8v*)(pb + s * 512);
            float av = asrc[h * 64 + cb * 16 + rlo];
            float dv = adst[h * 64 + cb * 16 + rlo];
            unsigned char* hph = hp + (size_t)h * Npad * 64;

            #pragma unroll
            for (int pp = 0; pp < 2; pp++) {
                int p = pg * 2 + pp;
                const half_t* pa = xt + (size_t)p * 4096 + lane * 8;
                f32x4 acc = (f32x4){0.f, 0.f, 0.f, 0.f};
                half8v A0 = *(const half8v*)(pa);
                half8v A1;
                #pragma unroll
                for (int s = 0; s < 8; s += 2) {
                    A1 = *(const half8v*)(pa + (s + 1) * 512);
                    acc = __builtin_amdgcn_mfma_f32_16x16x32_f16(A0, B[s], acc, 0, 0, 0);
                    if (s < 6) A0 = *(const half8v*)(pa + (s + 2) * 512);
                    acc = __builtin_amdgcn_mfma_f32_16x16x32_f16(A1, B[s + 1], acc, 0, 0, 0);
                }
                int grow = p * 16 + q * 4;
                unsigned pk0 = __builtin_amdgcn_cvt_pk_fp8_f32(acc[0], acc[1], 0, 0);
                pk0 = __builtin_amdgcn_cvt_pk_fp8_f32(acc[2], acc[3], pk0, 1);
                #pragma unroll
                for (int i = 0; i < 4; i++)
                    hph[(size_t)(grow + i) * 64 + cb * 16 + rlo] = (unsigned char)((pk0 >> (8 * i)) & 0xFF);

                float ps[4], pd[4];
                #pragma unroll
                for (int i = 0; i < 4; i++) { ps[i] = acc[i] * av; pd[i] = acc[i] * dv; }
                #pragma unroll
                for (int mask = 1; mask <= 8; mask <<= 1) {
                    #pragma unroll
                    for (int i = 0; i < 4; i++) {
                        ps[i] += __shfl_xor(ps[i], mask);
                        pd[i] += __shfl_xor(pd[i], mask);
                    }
                }
                if (rlo == 0) {
                    #pragma unroll
                    for (int i = 0; i < 4; i++) {
                        sp[pp][cb][q * 4 + i] = ps[i];
                        sd[pp][cb][q * 4 + i] = pd[i];
                    }
                }
            }
            __syncthreads();
            if (tid < 32) {
                int pp = tid >> 4, r = tid & 15;
                float s_ = sp[pp][0][r] + sp[pp][1][r] + sp[pp][2][r] + sp[pp][3][r];
                float d_ = sd[pp][0][r] + sd[pp][1][r] + sd[pp][2][r] + sd[pp][3][r];
                int grow = (pg * 2 + pp) * 16 + r;
                a_s[(size_t)grow * 4 + h] = s_;
                a_d[(size_t)grow * 4 + h] = d_;
            }
            __syncthreads();
        }
        __threadfence();
        gg.sync();

        // ---- aggregation phase ----
        for (int it = blockIdx.x; it < agg_items; it += gridDim.x) {
            int h = it & 3;
            int db = (it >> 2) * 16;
            int nn = lane >> 4;
            int d = db + wv * 4 + nn;
            if (d < N) {
                int r0 = row_ptr[d], deg = row_ptr[d + 1] - r0;
                float adv = a_d[(size_t)d * 4 + h];
                const unsigned char* hph = hp + (size_t)h * Npad * 64;

                if (deg <= AGGC) {
                    int le = lane & 15;
                    #pragma unroll
                    for (int k = 0; k < 3; k++) {
                        int e = k * 16 + le;
                        if (e < deg) {
                            int s = csr_src[r0 + e];
                            float ev = a_s[(size_t)s * 4 + h] + adv;
                            ev = ev > 0.f ? ev : NEG_SLOPE * ev;
                            pk[wv][nn][e][0] = __int_as_float(s);
                            pk[wv][nn][e][1] = __expf(ev - ESHIFT);
                        }
                    }
                    int es = (lane >> 3) & 1, chq = lane & 7;
                    const unsigned char* hpb = hph + chq * 8;
                    float c0 = 0.f, c1 = 0.f, c2 = 0.f, c3 = 0.f;
                    float c4 = 0.f, c5 = 0.f, c6 = 0.f, c7 = 0.f;
                    float asum = 0.f;
                    int full = deg >> 1;
                    int g = 0;
                    for (; g + 4 <= full; g += 4) {
                        AGG_BODY(g) AGG_BODY(g + 1) AGG_BODY(g + 2) AGG_BODY(g + 3)
                    }
                    for (; g < full; g++) { AGG_BODY(g) }
                    if ((deg & 1) && es == 0) {
                        int e_ = deg - 1;
                        int s_ = __float_as_int(pk[wv][nn][e_][0]);
                        float a_ = pk[wv][nn][e_][1];
                        const uint2 w_ = *(const uint2*)(hpb + (size_t)s_ * 64);
                        f32x2 f0 = __builtin_amdgcn_cvt_pk_f32_fp8(w_.x, 0);
                        f32x2 f1 = __builtin_amdgcn_cvt_pk_f32_fp8(w_.x, 1);
                        f32x2 f2 = __builtin_amdgcn_cvt_pk_f32_fp8(w_.y, 0);
                        f32x2 f3 = __builtin_amdgcn_cvt_pk_f32_fp8(w_.y, 1);
                        asum += a_;
                        c0 = fmaf(f0.x, a_, c0); c1 = fmaf(f0.y, a_, c1);
                        c2 = fmaf(f1.x, a_, c2); c3 = fmaf(f1.y, a_, c3);
                        c4 = fmaf(f2.x, a_, c4); c5 = fmaf(f2.y, a_, c5);
                        c6 = fmaf(f3.x, a_, c6); c7 = fmaf(f3.y, a_, c7);
                    }
                    c0 += __shfl_xor(c0, 8); c1 += __shfl_xor(c1, 8);
                    c2 += __shfl_xor(c2, 8); c3 += __shfl_xor(c3, 8);
                    c4 += __shfl_xor(c4, 8); c5 += __shfl_xor(c5, 8);
                    c6 += __shfl_xor(c6, 8); c7 += __shfl_xor(c7, 8);
                    asum += __shfl_xor(asum, 8);
                    if (es == 0) {
                        float inv = 1.0f / asum;
                        int o = h * 8 + chq;
                        const float* bp = bias + h * 64 + chq * 8;
                        float vv[8] = {c0, c1, c2, c3, c4, c5, c6, c7};
                        half_t oh[8] __attribute__((aligned(16)));
                        #pragma unroll
                        for (int j = 0; j < 8; j++) {
                            float v = vv[j] * inv + bp[j];
                            v = v > 0.f ? v : (__expf(v) - 1.0f);   // ELU
                            oh[j] = (half_t)v;
                        }
                        size_t dst = (size_t)(d >> 4) * 4096 + (o >> 2) * 512 + (o & 3) * 128 + (d & 15) * 8;
                        *(half8v*)(xt + dst) = *(half8v*)oh;
                    }
                } else {
                    int lc = lane & 15;
                    float cA = 0.f, cB = 0.f, cC = 0.f, cD = 0.f, asum = 0.f;
                    for (int i = 0; i < deg; i++) {
                        int s = csr_src[r0 + i];
                        float ev = a_s[(size_t)s * 4 + h] + adv;
                        ev = ev > 0.f ? ev : NEG_SLOPE * ev;
                        float a = __expf(ev - ESHIFT);
                        asum += a;
                        unsigned w = *(const unsigned*)(hph + (size_t)s * 64 + lc * 4);
                        f32x2 g0 = __builtin_amdgcn_cvt_pk_f32_fp8(w, 0);
                        f32x2 g1 = __builtin_amdgcn_cvt_pk_f32_fp8(w, 1);
                        cA = fmaf(g0.x, a, cA); cB = fmaf(g0.y, a, cB);
                        cC = fmaf(g1.x, a, cC); cD = fmaf(g1.y, a, cD);
                    }
                    float inv = 1.0f / asum;
                    int c = h * 64 + lc * 4;
                    float vv[4] = {cA, cB, cC, cD};
                    half_t oh[4] __attribute__((aligned(8)));
                    #pragma unroll
                    for (int j = 0; j < 4; j++) {
                        float v = vv[j] * inv + bias[c + j];
                        v = v > 0.f ? v : (__expf(v) - 1.0f);
                        oh[j] = (half_t)v;
                    }
                    size_t dst = (size_t)(d >> 4) * 4096 + (c >> 5) * 512 + ((c >> 3) & 3) * 128 + (d & 15) * 8 + (c & 7);
                    *(uint2*)(xt + dst) = *(uint2*)oh;
                }
            }
        }
        __threadfence();
        gg.sync();
    }
}

// ---------------- fallback separate kernels (R18 path, proven) ----------------
__global__ __launch_bounds__(256) void gemm_f16(
    const half_t* __restrict__ At, const half_t* __restrict__ Wt,
    const float* __restrict__ asrc, const float* __restrict__ adst,
    unsigned char* __restrict__ hp, float* __restrict__ as_out, float* __restrict__ ad_out,
    int Npad) {
    __shared__ float sp[4][4][16], sd[4][4][16];
    int nwg = gridDim.x;
    int bq = nwg >> 3, br = nwg & 7;
    int xcd = blockIdx.x & 7, bidx = blockIdx.x >> 3;
    int swz = (xcd < br ? xcd * (bq + 1) : br * (bq + 1) + (xcd - br) * bq) + bidx;
    int cb = threadIdx.x >> 6, lane = threadIdx.x & 63;
    int h = swz & 3, pg = swz >> 2;
    int rlo = lane & 15, q = lane >> 4;
    const half_t* pb = Wt + (size_t)h * 16384 + (size_t)cb * 4096 + lane * 8;

    half8v B[8];
    #pragma unroll
    for (int s = 0; s < 8; s++) B[s] = *(const half8v*)(pb + s * 512);

    float av = asrc[h * 64 + cb * 16 + rlo];
    float dv = adst[h * 64 + cb * 16 + rlo];
    unsigned char* hph = hp + (size_t)h * Npad * 64;

    #pragma unroll
    for (int pp = 0; pp < 4; pp++) {
        int p = pg * 4 + pp;
        const half_t* pa = At + (size_t)p * 4096 + lane * 8;
        f32x4 acc = (f32x4){0.f, 0.f, 0.f, 0.f};
        half8v A0 = *(const half8v*)(pa);
        half8v A1;
        #pragma unroll
        for (int s = 0; s < 8; s += 2) {
            A1 = *(const half8v*)(pa + (s + 1) * 512);
            acc = __builtin_amdgcn_mfma_f32_16x16x32_f16(A0, B[s], acc, 0, 0, 0);
            if (s < 6) A0 = *(const half8v*)(pa + (s + 2) * 512);
            acc = __builtin_amdgcn_mfma_f32_16x16x32_f16(A1, B[s + 1], acc, 0, 0, 0);
        }
        int grow = p * 16 + q * 4;
        unsigned pk0 = __builtin_amdgcn_cvt_pk_fp8_f32(acc[0], acc[1], 0, 0);
        pk0 = __builtin_amdgcn_cvt_pk_fp8_f32(acc[2], acc[3], pk0, 1);
        #pragma unroll
        for (int i = 0; i < 4; i++)
            hph[(size_t)(grow + i) * 64 + cb * 16 + rlo] = (unsigned char)((pk0 >> (8 * i)) & 0xFF);

        float ps[4], pd[4];
        #pragma unroll
        for (int i = 0; i < 4; i++) { ps[i] = acc[i] * av; pd[i] = acc[i] * dv; }
        #pragma unroll
        for (int mask = 1; mask <= 8; mask <<= 1) {
            #pragma unroll
            for (int i = 0; i < 4; i++) {
                ps[i] += __shfl_xor(ps[i], mask);
                pd[i] += __shfl_xor(pd[i], mask);
            }
        }
        if (rlo == 0) {
            #pragma unroll
            for (int i = 0; i < 4; i++) {
                sp[pp][cb][q * 4 + i] = ps[i];
                sd[pp][cb][q * 4 + i] = pd[i];
            }
        }
    }
    __syncthreads();
    if (threadIdx.x < 64) {
        int pp = threadIdx.x >> 4, r = threadIdx.x & 15;
        float s_ = sp[pp][0][r] + sp[pp][1][r] + sp[pp][2][r] + sp[pp][3][r];
        float d_ = sd[pp][0][r] + sd[pp][1][r] + sd[pp][2][r] + sd[pp][3][r];
        int grow = (pg * 4 + pp) * 16 + r;
        as_out[(size_t)grow * 4 + h] = s_;
        ad_out[(size_t)grow * 4 + h] = d_;
    }
}

__global__ __launch_bounds__(256) void gat_aggregate(
    const unsigned char* __restrict__ hp, const float* __restrict__ as_, const float* __restrict__ ad_,
    const int* __restrict__ row_ptr, const int* __restrict__ csr_src,
    const float* __restrict__ bias, half_t* __restrict__ hnext,
    int N, int Npad, int ngroups) {
    __shared__ float pk[4][4][AGGC][2];
    int wv = threadIdx.x >> 6, lane = threadIdx.x & 63;
    int h = blockIdx.x / ngroups;
    int db = (blockIdx.x % ngroups) * 16;
    int nn = lane >> 4;
    int d = db + wv * 4 + nn;
    if (d >= N) return;
    int r0 = row_ptr[d], deg = row_ptr[d + 1] - r0;
    float adv = ad_[(size_t)d * 4 + h];
    const unsigned char* hph = hp + (size_t)h * Npad * 64;

    if (deg <= AGGC) {
        int le = lane & 15;
        #pragma unroll
        for (int k = 0; k < 3; k++) {
            int e = k * 16 + le;
            if (e < deg) {
                int s = csr_src[r0 + e];
                float ev = as_[(size_t)s * 4 + h] + adv;
                ev = ev > 0.f ? ev : NEG_SLOPE * ev;
                pk[wv][nn][e][0] = __int_as_float(s);
                pk[wv][nn][e][1] = __expf(ev - ESHIFT);
            }
        }
        int es = (lane >> 3) & 1, chq = lane & 7;
        const unsigned char* hpb = hph + chq * 8;
        float c0 = 0.f, c1 = 0.f, c2 = 0.f, c3 = 0.f;
        float c4 = 0.f, c5 = 0.f, c6 = 0.f, c7 = 0.f;
        float asum = 0.f;
        int full = deg >> 1;
        int g = 0;
        for (; g + 4 <= full; g += 4) {
            AGG_BODY(g) AGG_BODY(g + 1) AGG_BODY(g + 2) AGG_BODY(g + 3)
        }
        for (; g < full; g++) { AGG_BODY(g) }
        if ((deg & 1) && es == 0) {
            int e_ = deg - 1;
            int s_ = __float_as_int(pk[wv][nn][e_][0]);
            float a_ = pk[wv][nn][e_][1];
            const uint2 w_ = *(const uint2*)(hpb + (size_t)s_ * 64);
            f32x2 f0 = __builtin_amdgcn_cvt_pk_f32_fp8(w_.x, 0);
            f32x2 f1 = __builtin_amdgcn_cvt_pk_f32_fp8(w_.x, 1);
            f32x2 f2 = __builtin_amdgcn_cvt_pk_f32_fp8(w_.y, 0);
            f32x2 f3 = __builtin_amdgcn_cvt_pk_f32_fp8(w_.y, 1);
            asum += a_;
            c0 = fmaf(f0.x, a_, c0); c1 = fmaf(f0.y, a_, c1);
            c2 = fmaf(f1.x, a_, c2); c3 = fmaf(f1.y, a_, c3);
            c4 = fmaf(f2.x, a_, c4); c5 = fmaf(f2.y, a_, c5);
            c6 = fmaf(f3.x, a_, c6); c7 = fmaf(f3.y, a_, c7);
        }
        c0 += __shfl_xor(c0, 8); c1 += __shfl_xor(c1, 8);
        c2 += __shfl_xor(c2, 8); c3 += __shfl_xor(c3, 8);
        c4 += __shfl_xor(c4, 8); c5 += __shfl_xor(c5, 8);
        c6 += __shfl_xor(c6, 8); c7 += __shfl_xor(c7, 8);
        asum += __shfl_xor(asum, 8);
        if (es == 0) {
            float inv = 1.0f / asum;
            int o = h * 8 + chq;
            const float* bp = bias + h * 64 + chq * 8;
            float vv[8] = {c0, c1, c2, c3, c4, c5, c6, c7};
            half_t oh[8] __attribute__((aligned(16)));
            #pragma unroll
            for (int j = 0; j < 8; j++) {
                float v = vv[j] * inv + bp[j];
                v = v > 0.f ? v : (__expf(v) - 1.0f);
                oh[j] = (half_t)v;
            }
            size_t dst = (size_t)(d >> 4) * 4096 + (o >> 2) * 512 + (o & 3) * 128 + (d & 15) * 8;
            *(half8v*)(hnext + dst) = *(half8v*)oh;
        }
    } else {
        int lc = lane & 15;
        float cA = 0.f, cB = 0.f, cC = 0.f, cD = 0.f, asum = 0.f;
        for (int i = 0; i < deg; i++) {
            int s = csr_src[r0 + i];
            float ev = as_[(size_t)s * 4 + h] + adv;
            ev = ev > 0.f ? ev : NEG_SLOPE * ev;
            float a = __expf(ev - ESHIFT);
            asum += a;
            unsigned w = *(const unsigned*)(hph + (size_t)s * 64 + lc * 4);
            f32x2 g0 = __builtin_amdgcn_cvt_pk_f32_fp8(w, 0);
            f32x2 g1 = __builtin_amdgcn_cvt_pk_f32_fp8(w, 1);
            cA = fmaf(g0.x, a, cA); cB = fmaf(g0.y, a, cB);
            cC = fmaf(g1.x, a, cC); cD = fmaf(g1.y, a, cD);
        }
        float inv = 1.0f / asum;
        int c = h * 64 + lc * 4;
        float vv[4] = {cA, cB, cC, cD};
        half_t oh[4] __attribute__((aligned(8)));
        #pragma unroll
        for (int j = 0; j < 4; j++) {
            float v = vv[j] * inv + bias[c + j];
            v = v > 0.f ? v : (__expf(v) - 1.0f);
            oh[j] = (half_t)v;
        }
        size_t dst = (size_t)(d >> 4) * 4096 + (c >> 5) * 512 + ((c >> 3) & 3) * 128 + (d & 15) * 8 + (c & 7);
        *(uint2*)(hnext + dst) = *(uint2*)oh;
    }
}

// ---------------- pooling + output head ----------------
__global__ __launch_bounds__(256) void col_sum_f16(const half_t* __restrict__ hin,
                                                   float* __restrict__ partial, int N, int rows_per_blk) {
    int c = threadIdx.x;
    int r0 = blockIdx.x * rows_per_blk;
    int r1 = min(r0 + rows_per_blk, N);
    int coff = (c >> 5) * 512 + ((c >> 3) & 3) * 128 + (c & 7);
    float acc = 0.f;
    for (int r = r0; r < r1; r++)
        acc += (float)hin[(size_t)(r >> 4) * 4096 + coff + (r & 15) * 8];
    partial[(size_t)blockIdx.x * 256 + c] = acc;
}

__global__ __launch_bounds__(256) void final_kernel(const float* __restrict__ partial,
                                                    const float* __restrict__ Wout,
                                                    const float* __restrict__ bout,
                                                    float* __restrict__ out, float invN, int nb) {
    __shared__ float gl[256];
    int j = threadIdx.x;
    float s = 0.f;
    for (int b = 0; b < nb; b++) s += partial[(size_t)b * 256 + j];
    gl[j] = s;
    __syncthreads();
    float acc = 0.f;
    for (int i = 0; i < 256; i++) acc += gl[i] * Wout[i * 256 + j];
    out[j] = acc * invN + bout[j];
}

extern "C" void kernel_launch(void* const* d_in, const int* in_sizes, int n_in,
                              void* d_out, int out_size, void* d_ws, size_t ws_size,
                              hipStream_t stream) {
    const float* x       = (const float*)d_in[0];
    const int*   ei      = (const int*)d_in[1];
    const float* Ws      = (const float*)d_in[2];
    const float* att_src = (const float*)d_in[3];
    const float* att_dst = (const float*)d_in[4];
    const float* biases  = (const float*)d_in[5];
    const float* Wout    = (const float*)d_in[6];
    const float* bout    = (const float*)d_in[7];
    float* out = (float*)d_out;

    int N = in_sizes[0] / D;          // 20000
    int E = in_sizes[1] / 2;          // 320000
    int L = in_sizes[2] / (D * D);    // 4
    int Etot = E + N;
    int Npad = (N + 63) & ~63;        // 20032

    char* ws = (char*)d_ws;
    size_t off = 0;
    auto alloc = [&](size_t bytes) -> void* {
        void* p = ws + off;
        off = (off + bytes + 255) & ~(size_t)255;
        return p;
    };
    half_t* xt         = (half_t*)alloc((size_t)Npad * D * 2);    // tiled A / h (f16)
    unsigned char* hp  = (unsigned char*)alloc((size_t)Npad * D); // fp8 head-major hp
    float* a_s         = (float*)alloc((size_t)Npad * H * 4);     // node-major [n][4]
    float* a_d         = (float*)alloc((size_t)Npad * H * 4);
    half_t* wt         = (half_t*)alloc((size_t)L * D * D * 2);   // fragment-linear W
    int*   counts      = (int*)alloc((size_t)N * 4);
    int*   row_ptr     = (int*)alloc((size_t)(N + 1) * 4);
    int*   cursor      = (int*)alloc((size_t)N * 4);
    int*   bsum        = (int*)alloc(64 * 4);
    int*   csr_src     = (int*)alloc((size_t)Etot * 4);
    int rows_per_blk = 254;
    int nb_pool = (N + rows_per_blk - 1) / rows_per_blk;     // 79
    float* partial = (float*)alloc((size_t)nb_pool * 256 * 4);
    if (off > ws_size) return;

    int thr = 256;

    // ---- conversions (tiled); conv_x also zeroes counts ----
    int xtot = N * 32;
    conv_x<<<(xtot + thr - 1) / thr, thr, 0, stream>>>(x, xt, xtot, counts, N);
    int wtot = L * 4 * 4 * 8 * 64;
    conv_w<<<(wtot + thr - 1) / thr, thr, 0, stream>>>(Ws, wt, wtot);

    // ---- CSR build ----
    count_kernel<<<(Etot + thr - 1) / thr, thr, 0, stream>>>(ei, E, N, counts);
    int nb_scan = (N + 1023) / 1024;  // 20
    scan1<<<nb_scan, 1024, 0, stream>>>(counts, row_ptr, bsum, N);
    scan3<<<nb_scan, 1024, 0, stream>>>(row_ptr, bsum, cursor, N, nb_scan);
    scatter_kernel<<<(Etot + thr - 1) / thr, thr, 0, stream>>>(ei, E, N, cursor, csr_src);

    // ---- layers: cooperative fused if the runtime accepts it, else proven separate path ----
    bool coop_done = false;
    {
        int dev = 0;
        hipGetDevice(&dev);
        int numCU = 0;
        hipDeviceGetAttribute(&numCU, hipDeviceAttributeMultiprocessorCount, dev);
        int perCU = 0;
        hipError_t qe = hipOccupancyMaxActiveBlocksPerMultiprocessor(
            &perCU, (const void*)fused_layers, 256, 0);
        int fgrid = (qe == hipSuccess && perCU > 0 && numCU > 0)
                        ? min(numCU * perCU, (Npad >> 5) * 4) : 0;
        if (fgrid > 0) {
            half_t* xt_ = xt; unsigned char* hp_ = hp;
            float* as_ = a_s; float* ad_ = a_d;
            const half_t* wt_ = wt;
            const float* asrc_ = att_src; const float* adst_ = att_dst; const float* bias_ = biases;
            const int* rp_ = row_ptr; const int* cs_ = csr_src;
            int N_ = N, Npad_ = Npad, L_ = L;
            void* kargs[] = {&xt_, &hp_, &as_, &ad_, &wt_, &asrc_, &adst_, &bias_,
                             &rp_, &cs_, &N_, &Npad_, &L_};
            hipError_t le = hipLaunchCooperativeKernel((void*)fused_layers, dim3(fgrid),
                                                       dim3(256), kargs, 0, stream);
            coop_done = (le == hipSuccess);
        }
    }
    if (!coop_done) {
        int gemm_blocks = (Npad / 64) * 4;   // 1252
        int ngroups = (N + 15) / 16;         // 1250
        int agg_blocks = 4 * ngroups;        // 5000
        for (int l = 0; l < L; l++) {
            gemm_f16<<<gemm_blocks, 256, 0, stream>>>(
                xt, wt + (size_t)l * D * D,
                att_src + (size_t)l * H * C, att_dst + (size_t)l * H * C,
                hp, a_s, a_d, Npad);
            gat_aggregate<<<agg_blocks, 256, 0, stream>>>(
                hp, a_s, a_d, row_ptr, csr_src, biases + (size_t)l * D, xt, N, Npad, ngroups);
        }
    }

    // ---- pool + head ----
    col_sum_f16<<<nb_pool, thr, 0, stream>>>(xt, partial, N, rows_per_blk);
    final_kernel<<<1, thr, 0, stream>>>(partial, Wout, bout, out, 1.0f / (float)N, nb_pool);
}

// Round 21
// 264.602 us; speedup vs baseline: 4.7529x; 4.7529x over previous
//
#include <hip/hip_runtime.h>
#include <hip/hip_bf16.h>

#define H 4
#define C 64
#define D 256
#define NEG_SLOPE 0.2f
#define ESHIFT 8.0f
#define AGGC 48

typedef _Float16 half_t;
typedef __attribute__((ext_vector_type(8))) _Float16 half8v;
typedef __attribute__((ext_vector_type(4))) float f32x4;

// Layouts:
//  - A / h ("xt"): fragment-linear tiled. panel = 16 rows; half-offset(r,c) =
//    (c>>5)*512 + ((c>>3)&3)*128 + r*8 + (c&7); wave frag load = panel*4096 + s*512 + lane*8.
//  - hp: HEAD-MAJOR hp[h][n][64] (per-head slab 2.56MB fits one XCD 4MiB L2).
//  - a_s / a_d: NODE-MAJOR [n][4].

// c_lo += f16lo(w)*a; c_hi += f16hi(w)*a  -- exact f32 fma with f16 source
__device__ inline void fma_mix_pair(float& clo, float& chi, unsigned wu, float a) {
    asm("v_fma_mix_f32 %0, %2, %3, %0 op_sel_hi:[1,0,0]\n\t"
        "v_fma_mix_f32 %1, %2, %3, %1 op_sel:[1,0,0] op_sel_hi:[1,0,0]"
        : "+v"(clo), "+v"(chi)
        : "v"(wu), "v"(a));
}

// ---------------- CSR build ----------------
__global__ void count_kernel(const int* __restrict__ ei, int E, int N, int* __restrict__ counts) {
    int i = blockIdx.x * blockDim.x + threadIdx.x;
    if (i >= E + N) return;
    int d = (i < E) ? ei[E + i] : (i - E);
    atomicAdd(&counts[d], 1);
}

__global__ __launch_bounds__(1024) void scan1(const int* __restrict__ counts,
                                              int* __restrict__ row_ptr,
                                              int* __restrict__ bsum, int N) {
    __shared__ int wsum[16];
    int tid = threadIdx.x, lane = tid & 63, wid = tid >> 6;
    int idx = blockIdx.x * 1024 + tid;
    int v = (idx < N) ? counts[idx] : 0;
    int val = v;
    #pragma unroll
    for (int o = 1; o < 64; o <<= 1) {
        int t = __shfl_up(val, o);
        if (lane >= o) val += t;
    }
    if (lane == 63) wsum[wid] = val;
    __syncthreads();
    int woff = 0;
    #pragma unroll
    for (int w = 0; w < 16; w++) woff += (w < wid) ? wsum[w] : 0;
    if (idx < N) row_ptr[idx] = woff + val - v;
    if (tid == 1023) bsum[blockIdx.x] = woff + val;
}

__global__ void scan2(int* __restrict__ bsum, int* __restrict__ row_ptr, int nb, int N) {
    int lane = threadIdx.x;
    int v = (lane < nb) ? bsum[lane] : 0;
    int val = v;
    #pragma unroll
    for (int o = 1; o < 64; o <<= 1) {
        int t = __shfl_up(val, o);
        if (lane >= o) val += t;
    }
    if (lane < nb) bsum[lane] = val - v;
    if (lane == 63) row_ptr[N] = val;
}

__global__ __launch_bounds__(1024) void scan3(int* __restrict__ row_ptr,
                                              const int* __restrict__ bsum,
                                              int* __restrict__ cursor, int N) {
    int idx = blockIdx.x * 1024 + threadIdx.x;
    if (idx >= N) return;
    int r = row_ptr[idx] + bsum[blockIdx.x];
    row_ptr[idx] = r;
    cursor[idx] = r;
}

__global__ void scatter_kernel(const int* __restrict__ ei, int E, int N,
                               int* __restrict__ cursor, int* __restrict__ csr_src) {
    int i = blockIdx.x * blockDim.x + threadIdx.x;
    if (i >= E + N) return;
    int s, d;
    if (i < E) { s = ei[i]; d = ei[E + i]; }
    else       { s = d = i - E; }
    int pos = atomicAdd(&cursor[d], 1);
    csr_src[pos] = s;
}

// ---------------- fp32 -> f16 tiled conversions ----------------
__global__ void conv_x(const float* __restrict__ in, half_t* __restrict__ xt, int total) {
    int t = blockIdx.x * blockDim.x + threadIdx.x;
    if (t >= total) return;
    int i = t >> 5, o = t & 31;
    const float* src = in + (size_t)i * 256 + o * 8;
    float4 v0 = *(const float4*)src;
    float4 v1 = *(const float4*)(src + 4);
    half_t q[8] __attribute__((aligned(16)));
    q[0] = (half_t)v0.x; q[1] = (half_t)v0.y; q[2] = (half_t)v0.z; q[3] = (half_t)v0.w;
    q[4] = (half_t)v1.x; q[5] = (half_t)v1.y; q[6] = (half_t)v1.z; q[7] = (half_t)v1.w;
    size_t dst = (size_t)(i >> 4) * 4096 + (o >> 2) * 512 + (o & 3) * 128 + (i & 15) * 8;
    *(half8v*)(xt + dst) = *(half8v*)q;
}

__global__ void conv_w(const float* __restrict__ W, half_t* __restrict__ wt, int total) {
    int idx = blockIdx.x * blockDim.x + threadIdx.x;
    if (idx >= total) return;   // total = L*4*4*8*64
    int Lr = idx & 63;
    int s  = (idx >> 6) & 7;
    int cb = (idx >> 9) & 3;
    int h  = (idx >> 11) & 3;
    int l  = idx >> 13;
    int col = h * 64 + cb * 16 + (Lr & 15);
    int k0  = 32 * s + (Lr >> 4) * 8;
    half_t q[8] __attribute__((aligned(16)));
    #pragma unroll
    for (int j = 0; j < 8; j++)
        q[j] = (half_t)W[(size_t)l * 65536 + (size_t)(k0 + j) * 256 + col];
    *(half8v*)(wt + (size_t)idx * 8) = *(half8v*)q;
}

// ---------------- persistent-B f16 MFMA GEMM + fused attention scores ----------------
// grid = (Npad/64 panel-groups) x 4 heads, XCD-swizzled; one barrier total.
__global__ __launch_bounds__(256) void gemm_f16(
    const half_t* __restrict__ At, const half_t* __restrict__ Wt,
    const float* __restrict__ asrc, const float* __restrict__ adst,
    half_t* __restrict__ hp, float* __restrict__ as_out, float* __restrict__ ad_out,
    int Npad) {
    __shared__ float sp[4][4][16], sd[4][4][16];
    int nwg = gridDim.x;
    int bq = nwg >> 3, br = nwg & 7;
    int xcd = blockIdx.x & 7, bidx = blockIdx.x >> 3;
    int swz = (xcd < br ? xcd * (bq + 1) : br * (bq + 1) + (xcd - br) * bq) + bidx;
    int cb = threadIdx.x >> 6, lane = threadIdx.x & 63;
    int h = swz & 3, pg = swz >> 2;
    int rlo = lane & 15, q = lane >> 4;
    const half_t* pb = Wt + (size_t)h * 16384 + (size_t)cb * 4096 + lane * 8;

    half8v B[8];
    #pragma unroll
    for (int s = 0; s < 8; s++) B[s] = *(const half8v*)(pb + s * 512);

    float av = asrc[h * 64 + cb * 16 + rlo];
    float dv = adst[h * 64 + cb * 16 + rlo];
    half_t* hph = hp + (size_t)h * Npad * 64;

    #pragma unroll
    for (int pp = 0; pp < 4; pp++) {
        int p = pg * 4 + pp;
        const half_t* pa = At + (size_t)p * 4096 + lane * 8;

        f32x4 acc = (f32x4){0.f, 0.f, 0.f, 0.f};
        half8v A0 = *(const half8v*)(pa);
        half8v A1;
        #pragma unroll
        for (int s = 0; s < 8; s += 2) {
            A1 = *(const half8v*)(pa + (s + 1) * 512);
            acc = __builtin_amdgcn_mfma_f32_16x16x32_f16(A0, B[s], acc, 0, 0, 0);
            if (s < 6) A0 = *(const half8v*)(pa + (s + 2) * 512);
            acc = __builtin_amdgcn_mfma_f32_16x16x32_f16(A1, B[s + 1], acc, 0, 0, 0);
        }

        int grow = p * 16 + q * 4;
        #pragma unroll
        for (int i = 0; i < 4; i++)
            hph[(size_t)(grow + i) * 64 + cb * 16 + rlo] = (half_t)acc[i];

        float ps[4], pd[4];
        #pragma unroll
        for (int i = 0; i < 4; i++) { ps[i] = acc[i] * av; pd[i] = acc[i] * dv; }
        #pragma unroll
        for (int mask = 1; mask <= 8; mask <<= 1) {
            #pragma unroll
            for (int i = 0; i < 4; i++) {
                ps[i] += __shfl_xor(ps[i], mask);
                pd[i] += __shfl_xor(pd[i], mask);
            }
        }
        if (rlo == 0) {
            #pragma unroll
            for (int i = 0; i < 4; i++) {
                sp[pp][cb][q * 4 + i] = ps[i];
                sd[pp][cb][q * 4 + i] = pd[i];
            }
        }
    }
    __syncthreads();
    if (threadIdx.x < 64) {
        int pp = threadIdx.x >> 4, r = threadIdx.x & 15;
        float s_ = sp[pp][0][r] + sp[pp][1][r] + sp[pp][2][r] + sp[pp][3][r];
        float d_ = sd[pp][0][r] + sd[pp][1][r] + sd[pp][2][r] + sd[pp][3][r];
        int grow = (pg * 4 + pp) * 16 + r;
        as_out[(size_t)grow * 4 + h] = s_;
        ad_out[(size_t)grow * 4 + h] = d_;
    }
}

// ---------------- GAT aggregation: head-phased, wave = 4 nodes x 1 head ----------------
#define AGG_BODY(g)                                                          \
    {                                                                        \
        int e_ = 2 * (g) + es;                                               \
        int s_ = __float_as_int(pk[wv][nn][e_][0]);                          \
        float a_ = pk[wv][nn][e_][1];                                        \
        const uint4 w_ = *(const uint4*)(hpb + (size_t)s_ * 64);             \
        asum += a_;                                                          \
        fma_mix_pair(c0, c1, w_.x, a_);                                      \
        fma_mix_pair(c2, c3, w_.y, a_);                                      \
        fma_mix_pair(c4, c5, w_.z, a_);                                      \
        fma_mix_pair(c6, c7, w_.w, a_);                                      \
    }

__global__ __launch_bounds__(256) void gat_aggregate(
    const half_t* __restrict__ hp, const float* __restrict__ as_, const float* __restrict__ ad_,
    const int* __restrict__ row_ptr, const int* __restrict__ csr_src,
    const float* __restrict__ bias, half_t* __restrict__ hnext,
    int N, int Npad, int ngroups) {
    __shared__ float pk[4][4][AGGC][2];   // [wave][node][edge][{src_bits, alpha}]
    int wv = threadIdx.x >> 6, lane = threadIdx.x & 63;
    int h = blockIdx.x / ngroups;
    int db = (blockIdx.x % ngroups) * 16;
    int nn = lane >> 4;
    int d = db + wv * 4 + nn;
    if (d >= N) return;
    int r0 = row_ptr[d], deg = row_ptr[d + 1] - r0;
    float adv = ad_[(size_t)d * 4 + h];
    const half_t* hph = hp + (size_t)h * Npad * 64;

    if (deg <= AGGC) {
        // phase A: 16 lanes/node load csr + a_s gather + exp -> LDS
        int le = lane & 15;
        #pragma unroll
        for (int k = 0; k < 3; k++) {
            int e = k * 16 + le;
            if (e < deg) {
                int s = csr_src[r0 + e];
                float ev = as_[(size_t)s * 4 + h] + adv;
                ev = ev > 0.f ? ev : NEG_SLOPE * ev;
                pk[wv][nn][e][0] = __int_as_float(s);
                pk[wv][nn][e][1] = __expf(ev - ESHIFT);
            }
        }
        // phase B: (es 0..1, chq 0..7) within the quarter
        int es = (lane >> 3) & 1, chq = lane & 7;
        const half_t* hpb = hph + chq * 8;
        float c0 = 0.f, c1 = 0.f, c2 = 0.f, c3 = 0.f;
        float c4 = 0.f, c5 = 0.f, c6 = 0.f, c7 = 0.f;
        float asum = 0.f;
        int full = deg >> 1;
        int g = 0;
        for (; g + 4 <= full; g += 4) {
            AGG_BODY(g) AGG_BODY(g + 1) AGG_BODY(g + 2) AGG_BODY(g + 3)
        }
        for (; g < full; g++) { AGG_BODY(g) }
        if ((deg & 1) && es == 0) {       // odd tail
            int e_ = deg - 1;
            int s_ = __float_as_int(pk[wv][nn][e_][0]);
            float a_ = pk[wv][nn][e_][1];
            const uint4 w_ = *(const uint4*)(hpb + (size_t)s_ * 64);
            asum += a_;
            fma_mix_pair(c0, c1, w_.x, a_);
            fma_mix_pair(c2, c3, w_.y, a_);
            fma_mix_pair(c4, c5, w_.z, a_);
            fma_mix_pair(c6, c7, w_.w, a_);
        }
        // reduce across the 2 slots (xor 8 stays within the 16-lane quarter)
        c0 += __shfl_xor(c0, 8); c1 += __shfl_xor(c1, 8);
        c2 += __shfl_xor(c2, 8); c3 += __shfl_xor(c3, 8);
        c4 += __shfl_xor(c4, 8); c5 += __shfl_xor(c5, 8);
        c6 += __shfl_xor(c6, 8); c7 += __shfl_xor(c7, 8);
        asum += __shfl_xor(asum, 8);
        // epilogue: es==0 lanes own octet o = h*8 + chq of node d
        if (es == 0) {
            float inv = 1.0f / asum;
            int o = h * 8 + chq;
            const float* bp = bias + h * 64 + chq * 8;
            float vv[8] = {c0, c1, c2, c3, c4, c5, c6, c7};
            half_t oh[8] __attribute__((aligned(16)));
            #pragma unroll
            for (int j = 0; j < 8; j++) {
                float v = vv[j] * inv + bp[j];
                v = v > 0.f ? v : (__expf(v) - 1.0f);   // ELU
                oh[j] = (half_t)v;
            }
            size_t dst = (size_t)(d >> 4) * 4096 + (o >> 2) * 512 + (o & 3) * 128 + (d & 15) * 8;
            *(half8v*)(hnext + dst) = *(half8v*)oh;
        }
    } else {
        // fallback (deg > AGGC): 16 lanes serial; lane owns 4 channels
        int lc = lane & 15;
        float cA = 0.f, cB = 0.f, cC = 0.f, cD = 0.f, asum = 0.f;
        for (int i = 0; i < deg; i++) {
            int s = csr_src[r0 + i];
            float ev = as_[(size_t)s * 4 + h] + adv;
            ev = ev > 0.f ? ev : NEG_SLOPE * ev;
            float a = __expf(ev - ESHIFT);
            asum += a;
            const uint2 w = *(const uint2*)(hph + (size_t)s * 64 + lc * 4);
            fma_mix_pair(cA, cB, w.x, a);
            fma_mix_pair(cC, cD, w.y, a);
        }
        float inv = 1.0f / asum;
        int c = h * 64 + lc * 4;
        float vv[4] = {cA, cB, cC, cD};
        half_t oh[4] __attribute__((aligned(8)));
        #pragma unroll
        for (int j = 0; j < 4; j++) {
            float v = vv[j] * inv + bias[c + j];
            v = v > 0.f ? v : (__expf(v) - 1.0f);
            oh[j] = (half_t)v;
        }
        size_t dst = (size_t)(d >> 4) * 4096 + (c >> 5) * 512 + ((c >> 3) & 3) * 128 + (d & 15) * 8 + (c & 7);
        *(uint2*)(hnext + dst) = *(uint2*)oh;
    }
}

// ---------------- pooling + output head ----------------
__global__ __launch_bounds__(256) void col_sum_f16(const half_t* __restrict__ hin,
                                                   float* __restrict__ partial, int N, int rows_per_blk) {
    int c = threadIdx.x;
    int r0 = blockIdx.x * rows_per_blk;
    int r1 = min(r0 + rows_per_blk, N);
    int coff = (c >> 5) * 512 + ((c >> 3) & 3) * 128 + (c & 7);
    float acc = 0.f;
    for (int r = r0; r < r1; r++)
        acc += (float)hin[(size_t)(r >> 4) * 4096 + coff + (r & 15) * 8];
    partial[(size_t)blockIdx.x * 256 + c] = acc;
}

__global__ __launch_bounds__(256) void final_kernel(const float* __restrict__ partial,
                                                    const float* __restrict__ Wout,
                                                    const float* __restrict__ bout,
                                                    float* __restrict__ out, float invN, int nb) {
    __shared__ float gl[256];
    int j = threadIdx.x;
    float s = 0.f;
    for (int b = 0; b < nb; b++) s += partial[(size_t)b * 256 + j];
    gl[j] = s;
    __syncthreads();
    float acc = 0.f;
    for (int i = 0; i < 256; i++) acc += gl[i] * Wout[i * 256 + j];
    out[j] = acc * invN + bout[j];
}

extern "C" void kernel_launch(void* const* d_in, const int* in_sizes, int n_in,
                              void* d_out, int out_size, void* d_ws, size_t ws_size,
                              hipStream_t stream) {
    const float* x       = (const float*)d_in[0];
    const int*   ei      = (const int*)d_in[1];
    const float* Ws      = (const float*)d_in[2];
    const float* att_src = (const float*)d_in[3];
    const float* att_dst = (const float*)d_in[4];
    const float* biases  = (const float*)d_in[5];
    const float* Wout    = (const float*)d_in[6];
    const float* bout    = (const float*)d_in[7];
    float* out = (float*)d_out;

    int N = in_sizes[0] / D;          // 20000
    int E = in_sizes[1] / 2;          // 320000
    int L = in_sizes[2] / (D * D);    // 4
    int Etot = E + N;
    int Npad = (N + 63) & ~63;        // 20032

    char* ws = (char*)d_ws;
    size_t off = 0;
    auto alloc = [&](size_t bytes) -> void* {
        void* p = ws + off;
        off = (off + bytes + 255) & ~(size_t)255;
        return p;
    };
    half_t* xt     = (half_t*)alloc((size_t)Npad * D * 2);   // tiled A / h
    half_t* hp     = (half_t*)alloc((size_t)Npad * D * 2);   // head-major hp
    float* a_s     = (float*)alloc((size_t)Npad * H * 4);    // node-major [n][4]
    float* a_d     = (float*)alloc((size_t)Npad * H * 4);
    half_t* wt     = (half_t*)alloc((size_t)L * D * D * 2);  // fragment-linear W
    int*   counts  = (int*)alloc((size_t)N * 4);
    int*   row_ptr = (int*)alloc((size_t)(N + 1) * 4);
    int*   cursor  = (int*)alloc((size_t)N * 4);
    int*   bsum    = (int*)alloc(64 * 4);
    int*   csr_src = (int*)alloc((size_t)Etot * 4);
    int rows_per_blk = 254;
    int nb_pool = (N + rows_per_blk - 1) / rows_per_blk;     // 79
    float* partial = (float*)alloc((size_t)nb_pool * 256 * 4);
    if (off > ws_size) return;

    int thr = 256;

    // ---- conversions (tiled) ----
    int xtot = N * 32;
    conv_x<<<(xtot + thr - 1) / thr, thr, 0, stream>>>(x, xt, xtot);
    int wtot = L * 4 * 4 * 8 * 64;
    conv_w<<<(wtot + thr - 1) / thr, thr, 0, stream>>>(Ws, wt, wtot);

    // ---- CSR build (parallel scan) ----
    hipMemsetAsync(counts, 0, (size_t)N * 4, stream);
    count_kernel<<<(Etot + thr - 1) / thr, thr, 0, stream>>>(ei, E, N, counts);
    int nb_scan = (N + 1023) / 1024;  // 20
    scan1<<<nb_scan, 1024, 0, stream>>>(counts, row_ptr, bsum, N);
    scan2<<<1, 64, 0, stream>>>(bsum, row_ptr, nb_scan, N);
    scan3<<<nb_scan, 1024, 0, stream>>>(row_ptr, bsum, cursor, N);
    scatter_kernel<<<(Etot + thr - 1) / thr, thr, 0, stream>>>(ei, E, N, cursor, csr_src);

    // ---- layers ----
    int gemm_blocks = (Npad / 64) * 4;   // 1252, XCD-swizzled in-kernel
    int ngroups = (N + 15) / 16;         // 1250
    int agg_blocks = 4 * ngroups;        // 5000, head-phased
    for (int l = 0; l < L; l++) {
        gemm_f16<<<gemm_blocks, 256, 0, stream>>>(
            xt, wt + (size_t)l * D * D,
            att_src + (size_t)l * H * C, att_dst + (size_t)l * H * C,
            hp, a_s, a_d, Npad);
        gat_aggregate<<<agg_blocks, 256, 0, stream>>>(
            hp, a_s, a_d, row_ptr, csr_src, biases + (size_t)l * D, xt, N, Npad, ngroups);
    }

    // ---- pool + head ----
    col_sum_f16<<<nb_pool, thr, 0, stream>>>(xt, partial, N, rows_per_blk);
    final_kernel<<<1, thr, 0, stream>>>(partial, Wout, bout, out, 1.0f / (float)N, nb_pool);
}